// Round 4
// baseline (2051.281 us; speedup 1.0000x reference)
//
#include <hip/hip_runtime.h>

#define H 1024
#define I_DIM 128
#define O_DIM 128
#define T_DIM 512
#define ALPHA 0.2f
#define NWG 64            // 4 batch-groups x 16 j-slices
#define GSZ 16            // WGs per batch-group
#define PLANE_U64 2048    // 64 slices x 32 octets, one u64 chunk each
#define GRP_U64   (3 * PLANE_U64)   // 6144 u64 = 48 KB per (parity, group)

typedef short short8 __attribute__((ext_vector_type(8)));
typedef float f32x4 __attribute__((ext_vector_type(4)));
typedef unsigned long long ull_alias __attribute__((may_alias));

__device__ __forceinline__ unsigned short f2b(float f) {
    union { float f; unsigned u; } x; x.f = f;
    unsigned u = x.u;
    return (unsigned short)((u + 0x7FFFu + ((u >> 16) & 1u)) >> 16);
}
__device__ __forceinline__ float tanh_fast(float x) {
    float e = __expf(2.0f * x);
    return 1.0f - 2.0f * __builtin_amdgcn_rcpf(e + 1.0f);
}
// 8 contiguous f32 -> bf16 fragment (RNE)
__device__ __forceinline__ short8 ld8f(const float* __restrict__ p) {
    const float4 a = *(const float4*)p;
    const float4 b = *(const float4*)(p + 4);
    short8 r;
    r[0]=(short)f2b(a.x); r[1]=(short)f2b(a.y); r[2]=(short)f2b(a.z); r[3]=(short)f2b(a.w);
    r[4]=(short)f2b(b.x); r[5]=(short)f2b(b.y); r[6]=(short)f2b(b.z); r[7]=(short)f2b(b.w);
    return r;
}
__device__ __forceinline__ short8 pack8(float4 a, float4 b) {
    short8 r;
    r[0]=(short)f2b(a.x); r[1]=(short)f2b(a.y); r[2]=(short)f2b(a.z); r[3]=(short)f2b(a.w);
    r[4]=(short)f2b(b.x); r[5]=(short)f2b(b.y); r[6]=(short)f2b(b.z); r[7]=(short)f2b(b.w);
    return r;
}
// Barrier that orders LDS only: NO vmcnt drain (this is the R4 change).
// __syncthreads() emits s_waitcnt vmcnt(0) before s_barrier, which serialized
// poll-load RTs and publish/out store ACKs into every step. All barriers in
// this kernel only hand off LDS (abuf/opart), so lgkmcnt(0) suffices.
__device__ __forceinline__ void bar_lgkm() {
    asm volatile("s_waitcnt lgkmcnt(0)\n\ts_barrier" ::: "memory");
}

// Packed-A layout per batch-group: A[m][k] at u16 offset
//   (k>>5)*512 + ((k&31)>>3)*128 + m*8 + (k&7)
// Cross-WG exchange: slice s = ji*4+w publishes 32 octets (o = m*2+so), each as
// THREE self-validating 8B chunks (48b data + 16b tag) at plane_p[s*32+o].
// Publish is fire-and-forget; the consumer's successful poll IS the fetch.
// R4: vmcnt-free barriers + poll issued right after publish, staying in flight
// across do_out + loop edge + x-MFMAs (~600cy cover ~= one LLC RT).
__global__ __launch_bounds__(256, 1) void rnn_kernel(
    const float* __restrict__ x, const float* __restrict__ wi,
    const float* __restrict__ wrec, const float* __restrict__ wout,
    const float* __restrict__ bb, const float* __restrict__ gg,
    const float* __restrict__ h0p, float* __restrict__ out,
    unsigned long long* __restrict__ aG)
{
    __shared__ unsigned short abuf[32 * 512];   // 32 KB: group's full a_{t-1}
    __shared__ unsigned short aloc[1024];       // 2 KB: own a_t slice, packed
    __shared__ float opart[4 * 128];            // 2 KB: out k-partials

    const int tid  = threadIdx.x;
    const int w    = tid >> 6, lane = tid & 63;
    const int n    = lane & 15, q = lane >> 4;
    const int grp  = blockIdx.x & 3;
    const int ji   = blockIdx.x >> 2;
    const int j0   = ji * 64;
    const int j    = j0 + w * 16 + n;           // this lane's owned h row
    const int b0   = grp * 16;

    // ---- register-resident weights (f32 -> bf16, once) ----
    short8 wfr[32];                              // wrec B-frags: B[k][j] = wrec[j][k]
#pragma unroll
    for (int kt = 0; kt < 32; ++kt)
        wfr[kt] = ld8f(&wrec[(size_t)j * H + kt * 32 + q * 8]);

    short8 wifr[4];                              // wi B-frags: B[k][j] = wi[k][j]
#pragma unroll
    for (int kt = 0; kt < 4; ++kt) {
        short8 v;
#pragma unroll
        for (int i = 0; i < 8; ++i)
            v[i] = (short)f2b(wi[(size_t)(kt * 32 + q * 8 + i) * H + j]);
        wifr[kt] = v;
    }
    short8 wofr[8];                              // wout B-frags, cols ji*8..+8, zero-pad n>=8
#pragma unroll
    for (int kk = 0; kk < 8; ++kk) {
        short8 v;
        const int kb = (w * 8 + kk) * 32 + q * 8;
#pragma unroll
        for (int i = 0; i < 8; ++i)
            v[i] = (n < 8) ? (short)f2b(wout[(size_t)(kb + i) * O_DIM + ji * 8 + n]) : (short)0;
        wofr[kk] = v;
    }

    const float gv = gg[j], bv = bb[j], h00 = h0p[j];
    float hreg[4];
#pragma unroll
    for (int r = 0; r < 4; ++r) hreg[r] = h00;

    const int kl    = w * 16 + n;                // local k in [0,64)
    const int off_l = (kl >> 5) * 512 + ((kl & 31) >> 3) * 128 + (kl & 7);
    const int s_sl  = ji * 4 + w;                // this wave's slice index

    unsigned long long* const gB0 = aG + grp * GRP_U64;            // parity 0
    unsigned long long* const gB1 = aG + (4 + grp) * GRP_U64;      // parity 1

    // publish chunk slots (lane-contiguous per half-wave / 32-lane group)
    const int pubA = (lane >> 5) * PLANE_U64 + s_sl * 32 + (lane & 31);  // parts 0/1
    const int pubB = 2 * PLANE_U64 + s_sl * 32 + lane;                    // part 2, lane<32
    const int oA   = lane & 31;

    // consume: remapped lane->octet so the unpack dest is linear.
    //   load u64 offset  = w*512 + perm(lane) + i*64  (contiguous 512B/instr)
    //   unpack dest byte = w*8192 + (i*64+lane)*16    (contiguous b128 writes)
    const int perm  = (lane >> 5) * 32 + (lane & 15) * 2 + ((lane >> 4) & 1);
    const int cb    = w * 512 + perm;

    // fire-and-forget: coalesced relaxed agent stores, chunks self-validating
    auto publish = [&](int t) {
        asm volatile("" ::: "memory");
        const unsigned long long tagv = (unsigned long long)(unsigned)t << 48;
        unsigned long long* gb = (t & 1) ? gB1 : gB0;
        {
            const ull_alias* opq = (const ull_alias*)&aloc[w * 256 + (oA & 1) * 128 + (oA >> 1) * 8];
            const unsigned long long lo = opq[0], hi = opq[1];
            const unsigned long long d0 = lo & 0x0000FFFFFFFFFFFFull;                        // v0 v1 v2
            const unsigned long long d1 = ((lo >> 48) | (hi << 16)) & 0x0000FFFFFFFFFFFFull; // v3 v4 v5
            __hip_atomic_store(gb + pubA, ((lane < 32) ? d0 : d1) | tagv,
                               __ATOMIC_RELAXED, __HIP_MEMORY_SCOPE_AGENT);
        }
        if (lane < 32) {
            const ull_alias* opq = (const ull_alias*)&aloc[w * 256 + (lane & 1) * 128 + (lane >> 1) * 8];
            const unsigned long long hi = opq[1];
            const unsigned long long d2 = ((hi >> 32) & 0xFFFFFFFFull) | tagv;               // v6 v7
            __hip_atomic_store(gb + pubB, d2, __ATOMIC_RELAXED, __HIP_MEMORY_SCOPE_AGENT);
        }
    };

    // speculative sample: 24 lane-contiguous loads into registers
    auto poll_issue = [&](const unsigned long long* gb,
                          unsigned long long* v0, unsigned long long* v1,
                          unsigned long long* v2) {
#pragma unroll
        for (int i = 0; i < 8; ++i) {
            v0[i] = __hip_atomic_load(gb + cb + i * 64,
                                      __ATOMIC_RELAXED, __HIP_MEMORY_SCOPE_AGENT);
            v1[i] = __hip_atomic_load(gb + PLANE_U64 + cb + i * 64,
                                      __ATOMIC_RELAXED, __HIP_MEMORY_SCOPE_AGENT);
            v2[i] = __hip_atomic_load(gb + 2 * PLANE_U64 + cb + i * 64,
                                      __ATOMIC_RELAXED, __HIP_MEMORY_SCOPE_AGENT);
        }
    };

    // late check: if any tag stale, fall back to the retry loop
    auto poll_check = [&](int tv, const unsigned long long* gb,
                          unsigned long long* v0, unsigned long long* v1,
                          unsigned long long* v2) {
        const unsigned tt = (unsigned)tv;
        for (;;) {
            unsigned bad = 0;
#pragma unroll
            for (int i = 0; i < 8; ++i)
                bad |= ((unsigned)(v0[i] >> 48) ^ tt) | ((unsigned)(v1[i] >> 48) ^ tt)
                     | ((unsigned)(v2[i] >> 48) ^ tt);
            if (__all(bad == 0)) break;
            __builtin_amdgcn_s_sleep(1);
            poll_issue(gb, v0, v1, v2);
        }
        asm volatile("" ::: "memory");
    };

    // recombine triples -> abuf, linear contiguous b128 writes
    auto unpack = [&](const unsigned long long* v0, const unsigned long long* v1,
                      const unsigned long long* v2) {
#pragma unroll
        for (int i = 0; i < 8; ++i) {
            const unsigned long long ca = v0[i], cb_ = v1[i], cc = v2[i];
            const unsigned long long w01 = (ca & 0xFFFFFFFFull)
                | (((ca >> 32) & 0xFFFFull) << 32) | ((cb_ & 0xFFFFull) << 48);   // v0..v3
            const unsigned long long w23 = ((cb_ >> 16) & 0xFFFFFFFFull) | (cc << 32); // v4..v7
            ull_alias* d = (ull_alias*)((char*)abuf + w * 8192 + (i * 64 + lane) * 16);
            d[0] = w01; d[1] = w23;
        }
    };

    // out[:, t, ji*8..+8) from abuf (full k=1024 chain); lgkm-only barrier inside
    auto do_out = [&](int t) {
        f32x4 oa = {0.f, 0.f, 0.f, 0.f};
#pragma unroll
        for (int kk = 0; kk < 8; ++kk) {
            short8 af = *(const short8*)&abuf[(w * 8 + kk) * 512 + lane * 8];
            oa = __builtin_amdgcn_mfma_f32_16x16x32_bf16(af, wofr[kk], oa, 0, 0, 0);
        }
        if (n < 8) {
#pragma unroll
            for (int r = 0; r < 4; ++r) opart[w * 128 + (4 * q + r) * 8 + n] = oa[r];
        }
        bar_lgkm();
        if (tid < 128) {
            float s = opart[tid] + opart[128 + tid] + opart[256 + tid] + opart[384 + tid];
            const int m = tid >> 3, c = tid & 7;
            out[((size_t)(b0 + m) * T_DIM + t) * O_DIM + ji * 8 + c] = s;
        }
    };

    // ---- init: stage + publish a0 = g*tanh(h0+b); speculative poll for step 0 ----
    {
        unsigned short a0 = f2b(gv * tanh_fast(h00 + bv));
#pragma unroll
        for (int r = 0; r < 4; ++r) aloc[off_l + (4 * q + r) * 8] = a0;
        publish(0);
    }
    unsigned long long pv0[8], pv1[8], pv2[8];   // speculative poll values
    poll_issue(gB0, pv0, pv1, pv2);

    short8 xfr[4];                               // packed x[:,0,:]
#pragma unroll
    for (int kt = 0; kt < 4; ++kt)
        xfr[kt] = ld8f(&x[(size_t)(b0 + n) * T_DIM * I_DIM + kt * 32 + q * 8]);

    float4 xr[8];                                // raw f32 prefetch (issue-early/pack-late)

    for (int t = 1; t < T_DIM; ++t) {
        const unsigned long long* gbp = ((t - 1) & 1) ? gB1 : gB0;  // pv source parity

        // next-step x loads: issue, consumed after check
        if (t < T_DIM - 1) {
            const float* xp = &x[((size_t)(b0 + n) * T_DIM + t) * I_DIM];
#pragma unroll
            for (int kt = 0; kt < 4; ++kt) {
                xr[2 * kt]     = *(const float4*)(xp + kt * 32 + q * 8);
                xr[2 * kt + 1] = *(const float4*)(xp + kt * 32 + q * 8 + 4);
            }
        }

        // x@wi partials: register-only, overlaps the in-flight poll/x loads
        f32x4 acc0 = {0.f,0.f,0.f,0.f}, acc1 = {0.f,0.f,0.f,0.f};
        acc0 = __builtin_amdgcn_mfma_f32_16x16x32_bf16(xfr[0], wifr[0], acc0, 0,0,0);
        acc1 = __builtin_amdgcn_mfma_f32_16x16x32_bf16(xfr[1], wifr[1], acc1, 0,0,0);
        acc0 = __builtin_amdgcn_mfma_f32_16x16x32_bf16(xfr[2], wifr[2], acc0, 0,0,0);
        acc1 = __builtin_amdgcn_mfma_f32_16x16x32_bf16(xfr[3], wifr[3], acc1, 0,0,0);

        bar_lgkm();               // all waves done reading abuf (do_out t-2); NO vmcnt drain
        poll_check(t - 1, gbp, pv0, pv1, pv2);   // polls had ~600cy of cover
        unpack(pv0, pv1, pv2);
        bar_lgkm();               // abuf complete & visible to all waves

        // + a_{t-1} @ wrec^T
#pragma unroll
        for (int kt = 0; kt < 32; kt += 2) {
            short8 a0f = *(const short8*)&abuf[kt * 512 + lane * 8];
            short8 a1f = *(const short8*)&abuf[(kt + 1) * 512 + lane * 8];
            acc0 = __builtin_amdgcn_mfma_f32_16x16x32_bf16(a0f, wfr[kt],     acc0, 0,0,0);
            acc1 = __builtin_amdgcn_mfma_f32_16x16x32_bf16(a1f, wfr[kt + 1], acc1, 0,0,0);
        }

        // h update; stage a_t in aloc (wave-private region), publish immediately
#pragma unroll
        for (int r = 0; r < 4; ++r) {
            float z  = acc0[r] + acc1[r];
            float hv = (1.0f - ALPHA) * hreg[r] + ALPHA * z;
            hreg[r] = hv;
            aloc[off_l + (4 * q + r) * 8] = f2b(gv * tanh_fast(hv + bv));
        }
        publish(t);
        // speculative poll for check(t) next iteration: stays in flight across
        // pack8 + do_out + loop edge + x-MFMAs (vmcnt-free barriers)
        poll_issue((t & 1) ? gB1 : gB0, pv0, pv1, pv2);

        if (t < T_DIM - 1) {
#pragma unroll
            for (int kt = 0; kt < 4; ++kt)
                xfr[kt] = pack8(xr[2 * kt], xr[2 * kt + 1]);
        }
        do_out(t - 1);            // reads abuf = a_{t-1}, written this iteration
    }

    // epilogue: out[:, 511, :] from a_511 (parity 1)
    bar_lgkm();
    poll_check(T_DIM - 1, gB1, pv0, pv1, pv2);
    unpack(pv0, pv1, pv2);
    bar_lgkm();
    do_out(T_DIM - 1);
}

extern "C" void kernel_launch(void* const* d_in, const int* in_sizes, int n_in,
                              void* d_out, int out_size, void* d_ws, size_t ws_size,
                              hipStream_t stream) {
    const float* x    = (const float*)d_in[0];
    const float* wi   = (const float*)d_in[1];
    const float* wrec = (const float*)d_in[2];
    const float* wout = (const float*)d_in[3];
    const float* bb   = (const float*)d_in[4];
    const float* gg   = (const float*)d_in[5];
    const float* h0   = (const float*)d_in[6];
    float* outp = (float*)d_out;

    unsigned long long* aG = (unsigned long long*)d_ws;   // 2 x 4 x 48 KB = 384 KB

    // reset all chunk tags to 0xFFFF (never matches any t < 512) so a graph
    // replay can't confuse the previous run's chunks with this run's
    hipMemsetAsync(d_ws, 0xFF, (size_t)2 * 4 * GRP_U64 * 8, stream);
    hipLaunchKernelGGL(rnn_kernel, dim3(NWG), dim3(256), 0, stream,
                       x, wi, wrec, wout, bb, gg, h0, outp, aG);
}

// Round 5
// 1791.845 us; speedup vs baseline: 1.1448x; 1.1448x over previous
//
#include <hip/hip_runtime.h>

#define H 1024
#define I_DIM 128
#define O_DIM 128
#define T_DIM 512
#define ALPHA 0.2f
#define NWG 64            // 4 batch-groups x 16 j-slices
#define GSZ 16            // WGs per batch-group
#define PLANE_U64 2048    // 64 slices x 32 octets, one u64 chunk each
#define GRP_U64   (3 * PLANE_U64)   // 6144 u64 = 48 KB per (parity, group)

typedef short short8 __attribute__((ext_vector_type(8)));
typedef float f32x4 __attribute__((ext_vector_type(4)));
typedef unsigned long long ull_alias __attribute__((may_alias));

__device__ __forceinline__ unsigned short f2b(float f) {
    union { float f; unsigned u; } x; x.f = f;
    unsigned u = x.u;
    return (unsigned short)((u + 0x7FFFu + ((u >> 16) & 1u)) >> 16);
}
__device__ __forceinline__ float tanh_fast(float x) {
    float e = __expf(2.0f * x);
    return 1.0f - 2.0f * __builtin_amdgcn_rcpf(e + 1.0f);
}
// 8 contiguous f32 -> bf16 fragment (RNE)
__device__ __forceinline__ short8 ld8f(const float* __restrict__ p) {
    const float4 a = *(const float4*)p;
    const float4 b = *(const float4*)(p + 4);
    short8 r;
    r[0]=(short)f2b(a.x); r[1]=(short)f2b(a.y); r[2]=(short)f2b(a.z); r[3]=(short)f2b(a.w);
    r[4]=(short)f2b(b.x); r[5]=(short)f2b(b.y); r[6]=(short)f2b(b.z); r[7]=(short)f2b(b.w);
    return r;
}
__device__ __forceinline__ short8 pack8(float4 a, float4 b) {
    short8 r;
    r[0]=(short)f2b(a.x); r[1]=(short)f2b(a.y); r[2]=(short)f2b(a.z); r[3]=(short)f2b(a.w);
    r[4]=(short)f2b(b.x); r[5]=(short)f2b(b.y); r[6]=(short)f2b(b.z); r[7]=(short)f2b(b.w);
    return r;
}
// Barrier that orders LDS only: NO vmcnt drain. __syncthreads() emits
// s_waitcnt vmcnt(0) before s_barrier, serializing poll-load RTs and
// publish/out store ACKs into every step. All barriers here hand off LDS
// (abuf/opart) only, so lgkmcnt(0) suffices. (R4 change, kept.)
__device__ __forceinline__ void bar_lgkm() {
    asm volatile("s_waitcnt lgkmcnt(0)\n\ts_barrier" ::: "memory");
}

// Packed-A layout per batch-group: A[m][k] at u16 offset
//   (k>>5)*512 + ((k&31)>>3)*128 + m*8 + (k&7)
// Cross-WG exchange: slice s = ji*4+w publishes 32 octets (o = m*2+so), each as
// THREE self-validating 8B chunks (48b data + 16b tag) at plane_p[s*32+o].
// Publish is fire-and-forget; the consumer's successful poll IS the fetch.
// R5 = R3 poll placement (loop-top sample: late in wall-clock -> first-check
// hits) + R4 vmcnt-free barriers (polls stay in flight across x-loads,
// x-MFMAs and the barrier; no store-ACK stalls). R4's post-publish sampling
// reverted: it sampled while peers were still publishing -> retries.
__global__ __launch_bounds__(256, 1) void rnn_kernel(
    const float* __restrict__ x, const float* __restrict__ wi,
    const float* __restrict__ wrec, const float* __restrict__ wout,
    const float* __restrict__ bb, const float* __restrict__ gg,
    const float* __restrict__ h0p, float* __restrict__ out,
    unsigned long long* __restrict__ aG)
{
    __shared__ unsigned short abuf[32 * 512];   // 32 KB: group's full a_{t-1}
    __shared__ unsigned short aloc[1024];       // 2 KB: own a_t slice, packed
    __shared__ float opart[4 * 128];            // 2 KB: out k-partials

    const int tid  = threadIdx.x;
    const int w    = tid >> 6, lane = tid & 63;
    const int n    = lane & 15, q = lane >> 4;
    const int grp  = blockIdx.x & 3;
    const int ji   = blockIdx.x >> 2;
    const int j0   = ji * 64;
    const int j    = j0 + w * 16 + n;           // this lane's owned h row
    const int b0   = grp * 16;

    // ---- register-resident weights (f32 -> bf16, once) ----
    short8 wfr[32];                              // wrec B-frags: B[k][j] = wrec[j][k]
#pragma unroll
    for (int kt = 0; kt < 32; ++kt)
        wfr[kt] = ld8f(&wrec[(size_t)j * H + kt * 32 + q * 8]);

    short8 wifr[4];                              // wi B-frags: B[k][j] = wi[k][j]
#pragma unroll
    for (int kt = 0; kt < 4; ++kt) {
        short8 v;
#pragma unroll
        for (int i = 0; i < 8; ++i)
            v[i] = (short)f2b(wi[(size_t)(kt * 32 + q * 8 + i) * H + j]);
        wifr[kt] = v;
    }
    short8 wofr[8];                              // wout B-frags, cols ji*8..+8, zero-pad n>=8
#pragma unroll
    for (int kk = 0; kk < 8; ++kk) {
        short8 v;
        const int kb = (w * 8 + kk) * 32 + q * 8;
#pragma unroll
        for (int i = 0; i < 8; ++i)
            v[i] = (n < 8) ? (short)f2b(wout[(size_t)(kb + i) * O_DIM + ji * 8 + n]) : (short)0;
        wofr[kk] = v;
    }

    const float gv = gg[j], bv = bb[j], h00 = h0p[j];
    float hreg[4];
#pragma unroll
    for (int r = 0; r < 4; ++r) hreg[r] = h00;

    const int kl    = w * 16 + n;                // local k in [0,64)
    const int off_l = (kl >> 5) * 512 + ((kl & 31) >> 3) * 128 + (kl & 7);
    const int s_sl  = ji * 4 + w;                // this wave's slice index

    unsigned long long* const gB0 = aG + grp * GRP_U64;            // parity 0
    unsigned long long* const gB1 = aG + (4 + grp) * GRP_U64;      // parity 1

    // publish chunk slots (lane-contiguous per half-wave / 32-lane group)
    const int pubA = (lane >> 5) * PLANE_U64 + s_sl * 32 + (lane & 31);  // parts 0/1
    const int pubB = 2 * PLANE_U64 + s_sl * 32 + lane;                    // part 2, lane<32
    const int oA   = lane & 31;

    // consume: remapped lane->octet so the unpack dest is linear.
    //   load u64 offset  = w*512 + perm(lane) + i*64  (contiguous 512B/instr)
    //   unpack dest byte = w*8192 + (i*64+lane)*16    (contiguous b128 writes)
    const int perm  = (lane >> 5) * 32 + (lane & 15) * 2 + ((lane >> 4) & 1);
    const int cb    = w * 512 + perm;

    // fire-and-forget: coalesced relaxed agent stores, chunks self-validating
    auto publish = [&](int t) {
        asm volatile("" ::: "memory");
        const unsigned long long tagv = (unsigned long long)(unsigned)t << 48;
        unsigned long long* gb = (t & 1) ? gB1 : gB0;
        {
            const ull_alias* opq = (const ull_alias*)&aloc[w * 256 + (oA & 1) * 128 + (oA >> 1) * 8];
            const unsigned long long lo = opq[0], hi = opq[1];
            const unsigned long long d0 = lo & 0x0000FFFFFFFFFFFFull;                        // v0 v1 v2
            const unsigned long long d1 = ((lo >> 48) | (hi << 16)) & 0x0000FFFFFFFFFFFFull; // v3 v4 v5
            __hip_atomic_store(gb + pubA, ((lane < 32) ? d0 : d1) | tagv,
                               __ATOMIC_RELAXED, __HIP_MEMORY_SCOPE_AGENT);
        }
        if (lane < 32) {
            const ull_alias* opq = (const ull_alias*)&aloc[w * 256 + (lane & 1) * 128 + (lane >> 1) * 8];
            const unsigned long long hi = opq[1];
            const unsigned long long d2 = ((hi >> 32) & 0xFFFFFFFFull) | tagv;               // v6 v7
            __hip_atomic_store(gb + pubB, d2, __ATOMIC_RELAXED, __HIP_MEMORY_SCOPE_AGENT);
        }
    };

    // speculative sample: 24 lane-contiguous loads into registers
    auto poll_issue = [&](const unsigned long long* gb,
                          unsigned long long* v0, unsigned long long* v1,
                          unsigned long long* v2) {
#pragma unroll
        for (int i = 0; i < 8; ++i) {
            v0[i] = __hip_atomic_load(gb + cb + i * 64,
                                      __ATOMIC_RELAXED, __HIP_MEMORY_SCOPE_AGENT);
            v1[i] = __hip_atomic_load(gb + PLANE_U64 + cb + i * 64,
                                      __ATOMIC_RELAXED, __HIP_MEMORY_SCOPE_AGENT);
            v2[i] = __hip_atomic_load(gb + 2 * PLANE_U64 + cb + i * 64,
                                      __ATOMIC_RELAXED, __HIP_MEMORY_SCOPE_AGENT);
        }
    };

    // late check: if any tag stale, fall back to the retry loop
    auto poll_check = [&](int tv, const unsigned long long* gb,
                          unsigned long long* v0, unsigned long long* v1,
                          unsigned long long* v2) {
        const unsigned tt = (unsigned)tv;
        for (;;) {
            unsigned bad = 0;
#pragma unroll
            for (int i = 0; i < 8; ++i)
                bad |= ((unsigned)(v0[i] >> 48) ^ tt) | ((unsigned)(v1[i] >> 48) ^ tt)
                     | ((unsigned)(v2[i] >> 48) ^ tt);
            if (__all(bad == 0)) break;
            __builtin_amdgcn_s_sleep(1);
            poll_issue(gb, v0, v1, v2);
        }
        asm volatile("" ::: "memory");
    };

    // recombine triples -> abuf, linear contiguous b128 writes
    auto unpack = [&](const unsigned long long* v0, const unsigned long long* v1,
                      const unsigned long long* v2) {
#pragma unroll
        for (int i = 0; i < 8; ++i) {
            const unsigned long long ca = v0[i], cb_ = v1[i], cc = v2[i];
            const unsigned long long w01 = (ca & 0xFFFFFFFFull)
                | (((ca >> 32) & 0xFFFFull) << 32) | ((cb_ & 0xFFFFull) << 48);   // v0..v3
            const unsigned long long w23 = ((cb_ >> 16) & 0xFFFFFFFFull) | (cc << 32); // v4..v7
            ull_alias* d = (ull_alias*)((char*)abuf + w * 8192 + (i * 64 + lane) * 16);
            d[0] = w01; d[1] = w23;
        }
    };

    // out[:, t, ji*8..+8) from abuf (full k=1024 chain); lgkm-only barrier inside
    auto do_out = [&](int t) {
        f32x4 oa = {0.f, 0.f, 0.f, 0.f};
#pragma unroll
        for (int kk = 0; kk < 8; ++kk) {
            short8 af = *(const short8*)&abuf[(w * 8 + kk) * 512 + lane * 8];
            oa = __builtin_amdgcn_mfma_f32_16x16x32_bf16(af, wofr[kk], oa, 0, 0, 0);
        }
        if (n < 8) {
#pragma unroll
            for (int r = 0; r < 4; ++r) opart[w * 128 + (4 * q + r) * 8 + n] = oa[r];
        }
        bar_lgkm();
        if (tid < 128) {
            float s = opart[tid] + opart[128 + tid] + opart[256 + tid] + opart[384 + tid];
            const int m = tid >> 3, c = tid & 7;
            out[((size_t)(b0 + m) * T_DIM + t) * O_DIM + ji * 8 + c] = s;
        }
    };

    // ---- init: stage + publish a0 = g*tanh(h0+b) (batch-broadcast) ----
    {
        unsigned short a0 = f2b(gv * tanh_fast(h00 + bv));
#pragma unroll
        for (int r = 0; r < 4; ++r) aloc[off_l + (4 * q + r) * 8] = a0;
        publish(0);
    }

    short8 xfr[4];                               // packed x[:,0,:]
#pragma unroll
    for (int kt = 0; kt < 4; ++kt)
        xfr[kt] = ld8f(&x[(size_t)(b0 + n) * T_DIM * I_DIM + kt * 32 + q * 8]);

    float4 xr[8];                                // raw f32 prefetch (issue-early/pack-late)
    unsigned long long pv0[8], pv1[8], pv2[8];   // speculative poll values

    for (int t = 1; t < T_DIM; ++t) {
        const unsigned long long* gbp = ((t - 1) & 1) ? gB1 : gB0;  // pv source parity

        // loop-top speculative sample (R3 placement): late in wall-clock, so
        // the first check usually hits; stays in flight through x-loads,
        // x-MFMAs and the vmcnt-free barrier below.
        poll_issue(gbp, pv0, pv1, pv2);

        // next-step x loads: issue, consumed after check
        if (t < T_DIM - 1) {
            const float* xp = &x[((size_t)(b0 + n) * T_DIM + t) * I_DIM];
#pragma unroll
            for (int kt = 0; kt < 4; ++kt) {
                xr[2 * kt]     = *(const float4*)(xp + kt * 32 + q * 8);
                xr[2 * kt + 1] = *(const float4*)(xp + kt * 32 + q * 8 + 4);
            }
        }

        // x@wi partials: register-only, overlaps the in-flight poll/x loads
        f32x4 acc0 = {0.f,0.f,0.f,0.f}, acc1 = {0.f,0.f,0.f,0.f};
        acc0 = __builtin_amdgcn_mfma_f32_16x16x32_bf16(xfr[0], wifr[0], acc0, 0,0,0);
        acc1 = __builtin_amdgcn_mfma_f32_16x16x32_bf16(xfr[1], wifr[1], acc1, 0,0,0);
        acc0 = __builtin_amdgcn_mfma_f32_16x16x32_bf16(xfr[2], wifr[2], acc0, 0,0,0);
        acc1 = __builtin_amdgcn_mfma_f32_16x16x32_bf16(xfr[3], wifr[3], acc1, 0,0,0);

        bar_lgkm();               // all waves done reading abuf (do_out t-2); NO vmcnt drain
        poll_check(t - 1, gbp, pv0, pv1, pv2);   // polls covered by x-work + barrier
        unpack(pv0, pv1, pv2);
        bar_lgkm();               // abuf complete & visible to all waves

        // + a_{t-1} @ wrec^T
#pragma unroll
        for (int kt = 0; kt < 32; kt += 2) {
            short8 a0f = *(const short8*)&abuf[kt * 512 + lane * 8];
            short8 a1f = *(const short8*)&abuf[(kt + 1) * 512 + lane * 8];
            acc0 = __builtin_amdgcn_mfma_f32_16x16x32_bf16(a0f, wfr[kt],     acc0, 0,0,0);
            acc1 = __builtin_amdgcn_mfma_f32_16x16x32_bf16(a1f, wfr[kt + 1], acc1, 0,0,0);
        }

        // h update; stage a_t in aloc (wave-private region), publish immediately
#pragma unroll
        for (int r = 0; r < 4; ++r) {
            float z  = acc0[r] + acc1[r];
            float hv = (1.0f - ALPHA) * hreg[r] + ALPHA * z;
            hreg[r] = hv;
            aloc[off_l + (4 * q + r) * 8] = f2b(gv * tanh_fast(hv + bv));
        }
        publish(t);

        // off critical path: pack the already-loaded x + out for step t-1
        if (t < T_DIM - 1) {
#pragma unroll
            for (int kt = 0; kt < 4; ++kt)
                xfr[kt] = pack8(xr[2 * kt], xr[2 * kt + 1]);
        }
        do_out(t - 1);            // reads abuf = a_{t-1}, written this iteration
    }

    // epilogue: out[:, 511, :] from a_511 (parity 1)
    poll_issue(gB1, pv0, pv1, pv2);
    bar_lgkm();
    poll_check(T_DIM - 1, gB1, pv0, pv1, pv2);
    unpack(pv0, pv1, pv2);
    bar_lgkm();
    do_out(T_DIM - 1);
}

extern "C" void kernel_launch(void* const* d_in, const int* in_sizes, int n_in,
                              void* d_out, int out_size, void* d_ws, size_t ws_size,
                              hipStream_t stream) {
    const float* x    = (const float*)d_in[0];
    const float* wi   = (const float*)d_in[1];
    const float* wrec = (const float*)d_in[2];
    const float* wout = (const float*)d_in[3];
    const float* bb   = (const float*)d_in[4];
    const float* gg   = (const float*)d_in[5];
    const float* h0   = (const float*)d_in[6];
    float* outp = (float*)d_out;

    unsigned long long* aG = (unsigned long long*)d_ws;   // 2 x 4 x 48 KB = 384 KB

    // reset all chunk tags to 0xFFFF (never matches any t < 512) so a graph
    // replay can't confuse the previous run's chunks with this run's
    hipMemsetAsync(d_ws, 0xFF, (size_t)2 * 4 * GRP_U64 * 8, stream);
    hipLaunchKernelGGL(rnn_kernel, dim3(NWG), dim3(256), 0, stream,
                       x, wi, wrec, wout, bb, gg, h0, outp, aG);
}